// Round 13
// baseline (95.792 us; speedup 1.0000x reference)
//
#include <hip/hip_runtime.h>
#include <math.h>

#define B    64
#define DQ   512
#define DO   256
#define NH   8
#define DH   32
#define HW   1024
#define NCH  16     // s-chunks per image
#define CHS  64     // s per chunk

// ---------------------------------------------------------------- k1: qv = q @ w_q.T + b_q   (wave-per-output GEMV)
__global__ __launch_bounds__(256) void k1_qv(const float* __restrict__ q,
                                             const float* __restrict__ w_q,
                                             const float* __restrict__ b_q,
                                             float* __restrict__ qv) {
    int cg = blockIdx.x, b = blockIdx.y;
    int t = threadIdx.x;
    int wid = t >> 6, lane = t & 63;
    const float4* qrow = reinterpret_cast<const float4*>(q + (size_t)b*DQ);
    float4 q0 = qrow[lane*2], q1 = qrow[lane*2 + 1];
    #pragma unroll
    for (int r = 0; r < 4; ++r) {
        int c = cg*16 + wid*4 + r;
        const float4* wrow = reinterpret_cast<const float4*>(w_q + (size_t)c*DQ);
        float4 w0 = wrow[lane*2], w1 = wrow[lane*2 + 1];
        float acc = q0.x*w0.x + q0.y*w0.y + q0.z*w0.z + q0.w*w0.w
                  + q1.x*w1.x + q1.y*w1.y + q1.z*w1.z + q1.w*w1.w;
        #pragma unroll
        for (int k = 32; k > 0; k >>= 1) acc += __shfl_xor(acc, k);
        if (lane == 0) qv[b*DO + c] = acc + b_q[c];
    }
}

// ---------------------------------------------------------------- k2: fold qv into kc/kd weights, TRANSPOSED out [b][c][n]
__global__ void k2_wqk(const float* __restrict__ qv,
                       const float* __restrict__ w_kc, const float* __restrict__ b_kc,
                       const float* __restrict__ w_kd, const float* __restrict__ b_kd,
                       const float* __restrict__ temp_c, const float* __restrict__ temp_d,
                       float* __restrict__ wqkcT, float* __restrict__ wqkdT,
                       float* __restrict__ qbc, float* __restrict__ qbd) {
    int bn = blockIdx.x;              // b*8 + n
    int n  = bn & 7;
    int bb = bn >> 3;
    int t  = threadIdx.x;             // c
    __shared__ float qvs[DH];
    if (t < DH) qvs[t] = qv[bb*DO + n*DH + t];
    __syncthreads();
    float itc = 1.0f / temp_c[0];
    float itd = 1.0f / temp_d[0];
    float ac = 0.f, ad = 0.f;
    #pragma unroll
    for (int d = 0; d < DH; ++d) {
        float qd = qvs[d];
        ac += qd * w_kc[(n*DH + d)*DO + t];
        ad += qd * w_kd[(n*DH + d)*DO + t];
    }
    wqkcT[((size_t)bb*DO + t)*NH + n] = ac * itc;
    wqkdT[((size_t)bb*DO + t)*NH + n] = ad * itd;
    if (t == 0) {
        float sc = 0.f;
        for (int d = 0; d < DH; ++d) sc += qvs[d]*b_kc[n*DH + d];
        qbc[bn] = sc * itc;
    }
    if (t == 1) {
        float sd = 0.f;
        for (int d = 0; d < DH; ++d) sd += qvs[d]*b_kd[n*DH + d];
        qbd[bn] = sd * itd;
    }
}

// ---------------------------------------------------------------- k3k: reg-held v, c-split waves, vectorized LDS only for exchange
// grid (NCH, B), block 512 (8 waves). Lane = (c4 = lane>>4, s4 = lane&15).
// Wave w owns c in [w*32, w*32+32); v loaded ONCE to registers (8 float4),
// used for logits then reused for pool. No LDS v tile.
__global__ __launch_bounds__(512, 4)
void k3k(const float* __restrict__ v,
         const float* __restrict__ wqkcT, const float* __restrict__ wqkdT,
         const float* __restrict__ qbc,  const float* __restrict__ qbd,
         float* __restrict__ gate, float* __restrict__ pvp, float* __restrict__ mz) {
    __shared__ float wt[2][DO][NH];        // 16 KB folded weights [cd][c][n]
    __shared__ float pex[2][NH][NH][CHS];  // 16 KB logit partials [cd][wave][n][s]
    __shared__ float e_lds[NH][CHS];       // 2 KB
    int ch = blockIdx.x, b = blockIdx.y;
    int t  = threadIdx.x;
    int s0 = ch*CHS;
    int bn0 = b*NH;
    int lane = t & 63;
    int w = __builtin_amdgcn_readfirstlane(t >> 6);
    int c4 = lane >> 4, s4 = lane & 15;
    int cbase = w*32;

    // ---- stage folded weights to LDS (coalesced; 2 float4 per thread)
    {
        const float4* sc_ = reinterpret_cast<const float4*>(wqkcT + (size_t)b*DO*NH);
        const float4* sd_ = reinterpret_cast<const float4*>(wqkdT + (size_t)b*DO*NH);
        reinterpret_cast<float4*>(&wt[0][0][0])[t] = sc_[t];
        reinterpret_cast<float4*>(&wt[1][0][0])[t] = sd_[t];
    }

    // ---- v into registers: 8 independent coalesced float4 loads
    float4 vreg[8];
    {
        const float* vb = v + (size_t)b*DO*HW + s0;
        #pragma unroll
        for (int ci = 0; ci < 8; ++ci) {
            int c = cbase + ci*4 + c4;
            vreg[ci] = *reinterpret_cast<const float4*>(vb + (size_t)c*HW + s4*4);
        }
    }
    __syncthreads();   // wt ready

    // ---- phase 1: logit partials, two passes of 4 heads (VGPR control)
    #pragma unroll
    for (int hp = 0; hp < 2; ++hp) {
        float acc_c[4][4] = {{0,0,0,0},{0,0,0,0},{0,0,0,0},{0,0,0,0}};
        float acc_d[4][4] = {{0,0,0,0},{0,0,0,0},{0,0,0,0},{0,0,0,0}};
        #pragma unroll
        for (int ci = 0; ci < 8; ++ci) {
            int c = cbase + ci*4 + c4;
            float4 wc4 = *reinterpret_cast<const float4*>(&wt[0][c][hp*4]);
            float4 wd4 = *reinterpret_cast<const float4*>(&wt[1][c][hp*4]);
            float4 vv = vreg[ci];
            float wcv[4] = {wc4.x, wc4.y, wc4.z, wc4.w};
            float wdv[4] = {wd4.x, wd4.y, wd4.z, wd4.w};
            #pragma unroll
            for (int n = 0; n < 4; ++n) {
                float a = wcv[n], d = wdv[n];
                acc_c[n][0] = fmaf(a, vv.x, acc_c[n][0]);
                acc_c[n][1] = fmaf(a, vv.y, acc_c[n][1]);
                acc_c[n][2] = fmaf(a, vv.z, acc_c[n][2]);
                acc_c[n][3] = fmaf(a, vv.w, acc_c[n][3]);
                acc_d[n][0] = fmaf(d, vv.x, acc_d[n][0]);
                acc_d[n][1] = fmaf(d, vv.y, acc_d[n][1]);
                acc_d[n][2] = fmaf(d, vv.z, acc_d[n][2]);
                acc_d[n][3] = fmaf(d, vv.w, acc_d[n][3]);
            }
        }
        // reduce over c4 groups (lane bits 4,5)
        #pragma unroll
        for (int n = 0; n < 4; ++n)
            #pragma unroll
            for (int j = 0; j < 4; ++j) {
                acc_c[n][j] += __shfl_xor(acc_c[n][j], 16);
                acc_c[n][j] += __shfl_xor(acc_c[n][j], 32);
                acc_d[n][j] += __shfl_xor(acc_d[n][j], 16);
                acc_d[n][j] += __shfl_xor(acc_d[n][j], 32);
            }
        if (c4 == 0) {
            #pragma unroll
            for (int n = 0; n < 4; ++n) {
                *reinterpret_cast<float4*>(&pex[0][w][hp*4+n][s4*4])
                    = make_float4(acc_c[n][0], acc_c[n][1], acc_c[n][2], acc_c[n][3]);
                *reinterpret_cast<float4*>(&pex[1][w][hp*4+n][s4*4])
                    = make_float4(acc_d[n][0], acc_d[n][1], acc_d[n][2], acc_d[n][3]);
            }
        }
    }
    __syncthreads();

    // ---- phase 2: wave w = head w; combine 8 waves' partials; gate + softmax stats
    {
        float lc = qbc[bn0 + w], ld = qbd[bn0 + w];
        #pragma unroll
        for (int k = 0; k < 8; ++k) {
            lc += pex[0][k][w][lane];
            ld += pex[1][k][w][lane];
        }
        gate[(size_t)(bn0 + w)*HW + s0 + lane] = 1.0f/(1.0f + __expf(-ld));
        float m = lc;
        #pragma unroll
        for (int k = 32; k > 0; k >>= 1) m = fmaxf(m, __shfl_xor(m, k));
        float e = __expf(lc - m);
        e_lds[w][lane] = e;
        float z = e;
        #pragma unroll
        for (int k = 32; k > 0; k >>= 1) z += __shfl_xor(z, k);
        if (lane == 0) {
            float* mzp = mz + ((size_t)(b*NCH + ch)*NH + w)*2;
            mzp[0] = m; mzp[1] = z;
        }
    }
    __syncthreads();

    // ---- phase 3: pool from vreg (no v re-read); e via b128 broadcast
    {
        float pool[8][8];
        #pragma unroll
        for (int n = 0; n < 8; ++n) {
            float4 e4 = *reinterpret_cast<const float4*>(&e_lds[n][s4*4]);
            #pragma unroll
            for (int ci = 0; ci < 8; ++ci) {
                float4 vv = vreg[ci];
                pool[n][ci] = vv.x*e4.x + vv.y*e4.y + vv.z*e4.z + vv.w*e4.w;
            }
        }
        // reduce over s4 (lane bits 0..3)
        #pragma unroll
        for (int n = 0; n < 8; ++n)
            #pragma unroll
            for (int ci = 0; ci < 8; ++ci) {
                pool[n][ci] += __shfl_xor(pool[n][ci], 1);
                pool[n][ci] += __shfl_xor(pool[n][ci], 2);
                pool[n][ci] += __shfl_xor(pool[n][ci], 4);
                pool[n][ci] += __shfl_xor(pool[n][ci], 8);
            }
        // write: lane (c4,s4) emits pool[s4>>1][(s4&1)*4 + k], k=0..3 (all lanes active)
        size_t pb = ((size_t)(b*NCH + ch)*NH)*DO;
        int wn = s4 >> 1;
        int ci0 = (s4 & 1)*4;
        float o0, o1, o2, o3;
        #pragma unroll
        for (int n = 0; n < 8; ++n) {
            #pragma unroll
            for (int ci = 0; ci < 8; ++ci) {
                if (n == 0 && ci == 0) { o0 = pool[0][0]; o1 = pool[0][4]; o2 = pool[0][1]; o3 = pool[0][5]; }
            }
        }
        // simpler explicit select (compile-time unrolled, lane-dependent pick via shuffle-free table):
        // emit 4 scattered stores; wn/ci0 are lane-varying so index pool via unrolled match
        #pragma unroll
        for (int k = 0; k < 4; ++k) {
            float val = 0.f;
            #pragma unroll
            for (int n = 0; n < 8; ++n)
                #pragma unroll
                for (int cj = 0; cj < 8; ++cj)
                    val = (n == wn && cj == ci0 + k) ? pool[n][cj] : val;
            pvp[pb + (size_t)wn*DO + cbase + (ci0 + k)*4 + c4] = val;
        }
    }
}

// ---------------------------------------------------------------- k4c: softmax-scale combine of 16 chunks + GEMV
__global__ void k4c(const float* __restrict__ pvp, const float* __restrict__ mz,
                    const float* __restrict__ w_v, const float* __restrict__ b_v,
                    float* __restrict__ attn) {
    __shared__ float scale[NCH][NH];
    __shared__ float pv_lds[NH*DO];
    int b = blockIdx.x, t = threadIdx.x;
    if (t < NH) {
        int n = t;
        float M = -1e30f;
        for (int ch = 0; ch < NCH; ++ch)
            M = fmaxf(M, mz[((size_t)(b*NCH+ch)*NH+n)*2]);
        float Z = 0.f;
        for (int ch = 0; ch < NCH; ++ch) {
            float sc = __expf(mz[((size_t)(b*NCH+ch)*NH+n)*2] - M);
            Z += sc * mz[((size_t)(b*NCH+ch)*NH+n)*2 + 1];
            scale[ch][n] = sc;
        }
        float inv = 1.0f/Z;
        for (int ch = 0; ch < NCH; ++ch) scale[ch][n] *= inv;
    }
    __syncthreads();
    #pragma unroll
    for (int r = 0; r < 2; ++r) {
        int i4 = t + r*256;              // float4 index, head = i4/64
        int n  = i4 >> 6;
        float4 s = make_float4(0.f, 0.f, 0.f, 0.f);
        #pragma unroll 4
        for (int ch = 0; ch < NCH; ++ch) {
            float sc = scale[ch][n];
            float4 p = reinterpret_cast<const float4*>(pvp + (size_t)(b*NCH + ch)*NH*DO)[i4];
            s.x = fmaf(sc, p.x, s.x); s.y = fmaf(sc, p.y, s.y);
            s.z = fmaf(sc, p.z, s.z); s.w = fmaf(sc, p.w, s.w);
        }
        *reinterpret_cast<float4*>(&pv_lds[i4*4]) = s;
    }
    __syncthreads();
    int n = t >> 5;
    float acc = b_v[t];
    const float4* w4 = reinterpret_cast<const float4*>(w_v + t*DO);
    #pragma unroll 4
    for (int c4 = 0; c4 < DO/4; ++c4) {
        float4 wv = w4[c4];
        int c = c4*4;
        acc += pv_lds[n*DO+c]*wv.x + pv_lds[n*DO+c+1]*wv.y + pv_lds[n*DO+c+2]*wv.z + pv_lds[n*DO+c+3]*wv.w;
    }
    attn[b*DO + t] = acc;
}

// ---------------------------------------------------------------- k5: out = leaky(bn(gate[s^T]*attn + v))
__global__ void k5_out(const float* __restrict__ v, const float* __restrict__ gate,
                       const float* __restrict__ attn,
                       const float* __restrict__ bn_g, const float* __restrict__ bn_b,
                       const float* __restrict__ bn_m, const float* __restrict__ bn_v,
                       float* __restrict__ out) {
    int c = blockIdx.x, b = blockIdx.y;
    int n = c >> 5, d = c & 31;
    int t = threadIdx.x;
    __shared__ float g[32*33];             // stride 33 kills transpose bank conflicts
    float4 gv = reinterpret_cast<const float4*>(gate + (b*NH + n)*HW)[t];
    int s0 = t*4;
    int ga = s0 >> 5, gb = s0 & 31;
    g[ga*33 + gb + 0] = gv.x;
    g[ga*33 + gb + 1] = gv.y;
    g[ga*33 + gb + 2] = gv.z;
    g[ga*33 + gb + 3] = gv.w;
    __syncthreads();
    float av   = attn[(b*NH + n)*DH + d];
    float inv  = bn_g[c] / sqrtf(bn_v[c] + 1e-5f);
    float mean = bn_m[c], beta = bn_b[c];
    size_t base = ((size_t)(b*DO + c))*HW;
    float4 r4 = reinterpret_cast<const float4*>(v + base)[t];
    int l = 4*t;
    int i_ = l >> 5, j_ = l & 31;          // gate index s = j*32 + i
    float x0 = g[(j_+0)*33 + i_]*av + r4.x;
    float x1 = g[(j_+1)*33 + i_]*av + r4.y;
    float x2 = g[(j_+2)*33 + i_]*av + r4.z;
    float x3 = g[(j_+3)*33 + i_]*av + r4.w;
    float y0 = (x0 - mean)*inv + beta; y0 = y0 >= 0.f ? y0 : 0.1f*y0;
    float y1 = (x1 - mean)*inv + beta; y1 = y1 >= 0.f ? y1 : 0.1f*y1;
    float y2 = (x2 - mean)*inv + beta; y2 = y2 >= 0.f ? y2 : 0.1f*y2;
    float y3 = (x3 - mean)*inv + beta; y3 = y3 >= 0.f ? y3 : 0.1f*y3;
    reinterpret_cast<float4*>(out + base)[t] = make_float4(y0, y1, y2, y3);
}

// ----------------------------------------------------------------
extern "C" void kernel_launch(void* const* d_in, const int* in_sizes, int n_in,
                              void* d_out, int out_size, void* d_ws, size_t ws_size,
                              hipStream_t stream) {
    const float* q      = (const float*)d_in[0];
    const float* v      = (const float*)d_in[1];
    const float* w_q    = (const float*)d_in[2];
    const float* b_q    = (const float*)d_in[3];
    const float* w_kc   = (const float*)d_in[4];
    const float* b_kc   = (const float*)d_in[5];
    const float* w_kd   = (const float*)d_in[6];
    const float* b_kd   = (const float*)d_in[7];
    const float* w_v    = (const float*)d_in[8];
    const float* b_v    = (const float*)d_in[9];
    const float* temp_c = (const float*)d_in[10];
    const float* temp_d = (const float*)d_in[11];
    const float* bn_g   = (const float*)d_in[12];
    const float* bn_b   = (const float*)d_in[13];
    const float* bn_m   = (const float*)d_in[14];
    const float* bn_v   = (const float*)d_in[15];
    float* out = (float*)d_out;

    float* ws    = (float*)d_ws;
    float* qv    = ws;                     // B*DO         = 16384
    float* wqkcT = qv    + B*DO;           // B*DO*NH      = 131072
    float* wqkdT = wqkcT + B*DO*NH;        // 131072
    float* qbc   = wqkdT + B*DO*NH;        // 512
    float* qbd   = qbc   + B*NH;           // 512
    float* gate  = qbd   + B*NH;           // B*NH*HW      = 524288
    float* mz    = gate  + B*NH*HW;        // B*NCH*NH*2   = 16384
    float* pvp   = mz    + B*NCH*NH*2;     // B*NCH*NH*DO  = 2097152
    float* attn  = pvp   + (size_t)B*NCH*NH*DO; // B*DO    = 16384

    k1_qv <<<dim3(16, B),    256, 0, stream>>>(q, w_q, b_q, qv);
    k2_wqk<<<B*NH,           256, 0, stream>>>(qv, w_kc, b_kc, w_kd, b_kd, temp_c, temp_d,
                                               wqkcT, wqkdT, qbc, qbd);
    k3k   <<<dim3(NCH, B),   512, 0, stream>>>(v, wqkcT, wqkdT, qbc, qbd, gate, pvp, mz);
    k4c   <<<B,              256, 0, stream>>>(pvp, mz, w_v, b_v, attn);
    k5_out<<<dim3(DO, B),    256, 0, stream>>>(v, gate, attn, bn_g, bn_b, bn_m, bn_v, out);
}

// Round 14
// 79.391 us; speedup vs baseline: 1.2066x; 1.2066x over previous
//
#include <hip/hip_runtime.h>
#include <math.h>

#define B    64
#define DQ   512
#define DO   256
#define NH   8
#define DH   32
#define HW   1024
#define NCH  8      // s-chunks per image
#define CHS  128    // s per chunk

// ---------------------------------------------------------------- k1: qv = q @ w_q.T + b_q   (wave-per-output GEMV)
__global__ __launch_bounds__(256) void k1_qv(const float* __restrict__ q,
                                             const float* __restrict__ w_q,
                                             const float* __restrict__ b_q,
                                             float* __restrict__ qv) {
    int cg = blockIdx.x, b = blockIdx.y;
    int t = threadIdx.x;
    int wid = t >> 6, lane = t & 63;
    const float4* qrow = reinterpret_cast<const float4*>(q + (size_t)b*DQ);
    float4 q0 = qrow[lane*2], q1 = qrow[lane*2 + 1];
    #pragma unroll
    for (int r = 0; r < 4; ++r) {
        int c = cg*16 + wid*4 + r;
        const float4* wrow = reinterpret_cast<const float4*>(w_q + (size_t)c*DQ);
        float4 w0 = wrow[lane*2], w1 = wrow[lane*2 + 1];
        float acc = q0.x*w0.x + q0.y*w0.y + q0.z*w0.z + q0.w*w0.w
                  + q1.x*w1.x + q1.y*w1.y + q1.z*w1.z + q1.w*w1.w;
        #pragma unroll
        for (int k = 32; k > 0; k >>= 1) acc += __shfl_xor(acc, k);
        if (lane == 0) qv[b*DO + c] = acc + b_q[c];
    }
}

// ---------------------------------------------------------------- k2: fold qv into kc/kd weights
__global__ void k2_wqk(const float* __restrict__ qv,
                       const float* __restrict__ w_kc, const float* __restrict__ b_kc,
                       const float* __restrict__ w_kd, const float* __restrict__ b_kd,
                       const float* __restrict__ temp_c, const float* __restrict__ temp_d,
                       float* __restrict__ wqkc, float* __restrict__ wqkd,
                       float* __restrict__ qbc, float* __restrict__ qbd) {
    int bn = blockIdx.x;              // b*8 + n
    int n  = bn & 7;
    int t  = threadIdx.x;             // c
    __shared__ float qvs[DH];
    if (t < DH) qvs[t] = qv[(bn >> 3)*DO + n*DH + t];
    __syncthreads();
    float itc = 1.0f / temp_c[0];
    float itd = 1.0f / temp_d[0];
    float ac = 0.f, ad = 0.f;
    #pragma unroll
    for (int d = 0; d < DH; ++d) {
        float qd = qvs[d];
        ac += qd * w_kc[(n*DH + d)*DO + t];
        ad += qd * w_kd[(n*DH + d)*DO + t];
    }
    wqkc[bn*DO + t] = ac * itc;
    wqkd[bn*DO + t] = ad * itd;
    if (t == 0) {
        float sc = 0.f;
        for (int d = 0; d < DH; ++d) sc += qvs[d]*b_kc[n*DH + d];
        qbc[bn] = sc * itc;
    }
    if (t == 1) {
        float sd = 0.f;
        for (int d = 0; d < DH; ++d) sd += qvs[d]*b_kd[n*DH + d];
        qbd[bn] = sd * itd;
    }
}

// ---------------------------------------------------------------- k3m: = round-10 k3h with FULL-BATCH register loads in phase 1
// grid (NCH=8, B) = 512 blocks (2/CU via 68KB LDS), block 512 (8 waves), 16 waves/CU.
__global__ __launch_bounds__(512, 2)
void k3m(const float* __restrict__ v,
         const float* __restrict__ wqkc, const float* __restrict__ wqkd,
         const float* __restrict__ qbc,  const float* __restrict__ qbd,
         float* __restrict__ gate, float* __restrict__ pvp, float* __restrict__ mz) {
    __shared__ float pc[8*NH*CHS];       // 32 KB collect partials [csub][n][s]
    __shared__ float pd[8*NH*CHS];       // 32 KB diffuse partials
    __shared__ float e_lds[NH][CHS];     // 4 KB
    int ch = blockIdx.x, b = blockIdx.y;
    int t  = threadIdx.x;
    int s0 = ch*CHS;
    int bn0 = b*NH;
    int lane = t & 63;
    int sl2  = lane*2;
    int csub = __builtin_amdgcn_readfirstlane(t >> 6);

    // ---- phase 1: ALL 32 v-loads issued before any use (one vmcnt drain),
    //      then pure-FMA consumption. Wave csub owns 32 channels, all 8 heads.
    {
        const float* vb = v + (size_t)b*DO*HW + s0 + sl2;
        const float* wc = wqkc + (size_t)bn0*DO;
        const float* wd = wqkd + (size_t)bn0*DO;
        int cbase = csub*32;

        float2 vv[32];
        #pragma unroll
        for (int cc = 0; cc < 32; ++cc)
            vv[cc] = *reinterpret_cast<const float2*>(vb + (size_t)(cbase + cc)*HW);

        float acc_c0[NH] = {0,0,0,0,0,0,0,0}, acc_c1[NH] = {0,0,0,0,0,0,0,0};
        float acc_d0[NH] = {0,0,0,0,0,0,0,0}, acc_d1[NH] = {0,0,0,0,0,0,0,0};
        #pragma unroll
        for (int cc = 0; cc < 32; ++cc) {
            int c = cbase + cc;
            float2 v2 = vv[cc];
            #pragma unroll
            for (int n = 0; n < NH; ++n) {
                float wcv = wc[n*DO + c];     // wave-uniform -> scalar load
                float wdv = wd[n*DO + c];
                acc_c0[n] = fmaf(wcv, v2.x, acc_c0[n]);
                acc_c1[n] = fmaf(wcv, v2.y, acc_c1[n]);
                acc_d0[n] = fmaf(wdv, v2.x, acc_d0[n]);
                acc_d1[n] = fmaf(wdv, v2.y, acc_d1[n]);
            }
        }
        #pragma unroll
        for (int n = 0; n < NH; ++n) {
            *reinterpret_cast<float2*>(&pc[(csub*NH + n)*CHS + sl2]) = make_float2(acc_c0[n], acc_c1[n]);
            *reinterpret_cast<float2*>(&pd[(csub*NH + n)*CHS + sl2]) = make_float2(acc_d0[n], acc_d1[n]);
        }
    }
    __syncthreads();

    // ---- phase 2: wave n combines csub partials for head n; softmax + gate, wave-local
    {
        int n = csub;
        float lc0 = qbc[bn0+n], lc1 = lc0;
        float ld0 = qbd[bn0+n], ld1 = ld0;
        #pragma unroll
        for (int k = 0; k < 8; ++k) {
            float2 c2 = *reinterpret_cast<const float2*>(&pc[(k*NH + n)*CHS + sl2]);
            float2 d2 = *reinterpret_cast<const float2*>(&pd[(k*NH + n)*CHS + sl2]);
            lc0 += c2.x; lc1 += c2.y;
            ld0 += d2.x; ld1 += d2.y;
        }
        float g0 = 1.0f/(1.0f + __expf(-ld0));
        float g1 = 1.0f/(1.0f + __expf(-ld1));
        *reinterpret_cast<float2*>(gate + (size_t)(bn0+n)*HW + s0 + sl2) = make_float2(g0, g1);

        float m = fmaxf(lc0, lc1);
        #pragma unroll
        for (int k = 32; k > 0; k >>= 1) m = fmaxf(m, __shfl_xor(m, k));
        float e0 = __expf(lc0 - m), e1 = __expf(lc1 - m);
        float z = e0 + e1;
        #pragma unroll
        for (int k = 32; k > 0; k >>= 1) z += __shfl_xor(z, k);
        *reinterpret_cast<float2*>(&e_lds[n][sl2]) = make_float2(e0, e1);
        if (lane == 0) {
            float* mzp = mz + ((size_t)(b*NCH + ch)*NH + n)*2;
            mzp[0] = m; mzp[1] = z;
        }
    }
    __syncthreads();

    // ---- phase 3: partial pool, transposed mapping: thread -> (c, 4 heads), s serial (L1/L2-hot)
    {
        int ng = t >> 8;                 // 0 or 1
        int c  = t & 255;
        const float* vrow = v + ((size_t)(b*DO + c))*HW + s0;
        float a0 = 0.f, a1 = 0.f, a2 = 0.f, a3 = 0.f;
        #pragma unroll 4
        for (int j = 0; j < CHS/4; ++j) {
            float4 v4 = *reinterpret_cast<const float4*>(vrow + j*4);
            float4 e0 = *reinterpret_cast<const float4*>(&e_lds[ng*4+0][j*4]);
            float4 e1 = *reinterpret_cast<const float4*>(&e_lds[ng*4+1][j*4]);
            float4 e2 = *reinterpret_cast<const float4*>(&e_lds[ng*4+2][j*4]);
            float4 e3 = *reinterpret_cast<const float4*>(&e_lds[ng*4+3][j*4]);
            a0 += v4.x*e0.x + v4.y*e0.y + v4.z*e0.z + v4.w*e0.w;
            a1 += v4.x*e1.x + v4.y*e1.y + v4.z*e1.z + v4.w*e1.w;
            a2 += v4.x*e2.x + v4.y*e2.y + v4.z*e2.z + v4.w*e2.w;
            a3 += v4.x*e3.x + v4.y*e3.y + v4.z*e3.z + v4.w*e3.w;
        }
        size_t pb = ((size_t)(b*NCH + ch)*NH + ng*4)*DO + c;
        pvp[pb]        = a0;
        pvp[pb + DO]   = a1;
        pvp[pb + 2*DO] = a2;
        pvp[pb + 3*DO] = a3;
    }
}

// ---------------------------------------------------------------- k4c: softmax-scale combine of 8 chunks + GEMV
__global__ void k4c(const float* __restrict__ pvp, const float* __restrict__ mz,
                    const float* __restrict__ w_v, const float* __restrict__ b_v,
                    float* __restrict__ attn) {
    __shared__ float scale[NCH][NH];
    __shared__ float pv_lds[NH*DO];
    int b = blockIdx.x, t = threadIdx.x;
    if (t < NH) {
        int n = t;
        float M = -1e30f;
        for (int ch = 0; ch < NCH; ++ch)
            M = fmaxf(M, mz[((size_t)(b*NCH+ch)*NH+n)*2]);
        float Z = 0.f;
        for (int ch = 0; ch < NCH; ++ch) {
            float sc = __expf(mz[((size_t)(b*NCH+ch)*NH+n)*2] - M);
            Z += sc * mz[((size_t)(b*NCH+ch)*NH+n)*2 + 1];
            scale[ch][n] = sc;
        }
        float inv = 1.0f/Z;
        for (int ch = 0; ch < NCH; ++ch) scale[ch][n] *= inv;
    }
    __syncthreads();
    #pragma unroll
    for (int r = 0; r < 2; ++r) {
        int i4 = t + r*256;              // float4 index, head = i4/64
        int n  = i4 >> 6;
        float4 s = make_float4(0.f, 0.f, 0.f, 0.f);
        #pragma unroll
        for (int ch = 0; ch < NCH; ++ch) {
            float sc = scale[ch][n];
            float4 p = reinterpret_cast<const float4*>(pvp + (size_t)(b*NCH + ch)*NH*DO)[i4];
            s.x = fmaf(sc, p.x, s.x); s.y = fmaf(sc, p.y, s.y);
            s.z = fmaf(sc, p.z, s.z); s.w = fmaf(sc, p.w, s.w);
        }
        *reinterpret_cast<float4*>(&pv_lds[i4*4]) = s;
    }
    __syncthreads();
    int n = t >> 5;
    float acc = b_v[t];
    const float4* w4 = reinterpret_cast<const float4*>(w_v + t*DO);
    #pragma unroll 4
    for (int c4 = 0; c4 < DO/4; ++c4) {
        float4 wv = w4[c4];
        int c = c4*4;
        acc += pv_lds[n*DO+c]*wv.x + pv_lds[n*DO+c+1]*wv.y + pv_lds[n*DO+c+2]*wv.z + pv_lds[n*DO+c+3]*wv.w;
    }
    attn[b*DO + t] = acc;
}

// ---------------------------------------------------------------- k5: out = leaky(bn(gate[s^T]*attn + v))
__global__ void k5_out(const float* __restrict__ v, const float* __restrict__ gate,
                       const float* __restrict__ attn,
                       const float* __restrict__ bn_g, const float* __restrict__ bn_b,
                       const float* __restrict__ bn_m, const float* __restrict__ bn_v,
                       float* __restrict__ out) {
    int c = blockIdx.x, b = blockIdx.y;
    int n = c >> 5, d = c & 31;
    int t = threadIdx.x;
    __shared__ float g[32*33];             // stride 33 kills transpose bank conflicts
    float4 gv = reinterpret_cast<const float4*>(gate + (b*NH + n)*HW)[t];
    int s0 = t*4;
    int ga = s0 >> 5, gb = s0 & 31;
    g[ga*33 + gb + 0] = gv.x;
    g[ga*33 + gb + 1] = gv.y;
    g[ga*33 + gb + 2] = gv.z;
    g[ga*33 + gb + 3] = gv.w;
    __syncthreads();
    float av   = attn[(b*NH + n)*DH + d];
    float inv  = bn_g[c] / sqrtf(bn_v[c] + 1e-5f);
    float mean = bn_m[c], beta = bn_b[c];
    size_t base = ((size_t)(b*DO + c))*HW;
    float4 r4 = reinterpret_cast<const float4*>(v + base)[t];
    int l = 4*t;
    int i_ = l >> 5, j_ = l & 31;          // gate index s = j*32 + i
    float x0 = g[(j_+0)*33 + i_]*av + r4.x;
    float x1 = g[(j_+1)*33 + i_]*av + r4.y;
    float x2 = g[(j_+2)*33 + i_]*av + r4.z;
    float x3 = g[(j_+3)*33 + i_]*av + r4.w;
    float y0 = (x0 - mean)*inv + beta; y0 = y0 >= 0.f ? y0 : 0.1f*y0;
    float y1 = (x1 - mean)*inv + beta; y1 = y1 >= 0.f ? y1 : 0.1f*y1;
    float y2 = (x2 - mean)*inv + beta; y2 = y2 >= 0.f ? y2 : 0.1f*y2;
    float y3 = (x3 - mean)*inv + beta; y3 = y3 >= 0.f ? y3 : 0.1f*y3;
    reinterpret_cast<float4*>(out + base)[t] = make_float4(y0, y1, y2, y3);
}

// ----------------------------------------------------------------
extern "C" void kernel_launch(void* const* d_in, const int* in_sizes, int n_in,
                              void* d_out, int out_size, void* d_ws, size_t ws_size,
                              hipStream_t stream) {
    const float* q      = (const float*)d_in[0];
    const float* v      = (const float*)d_in[1];
    const float* w_q    = (const float*)d_in[2];
    const float* b_q    = (const float*)d_in[3];
    const float* w_kc   = (const float*)d_in[4];
    const float* b_kc   = (const float*)d_in[5];
    const float* w_kd   = (const float*)d_in[6];
    const float* b_kd   = (const float*)d_in[7];
    const float* w_v    = (const float*)d_in[8];
    const float* b_v    = (const float*)d_in[9];
    const float* temp_c = (const float*)d_in[10];
    const float* temp_d = (const float*)d_in[11];
    const float* bn_g   = (const float*)d_in[12];
    const float* bn_b   = (const float*)d_in[13];
    const float* bn_m   = (const float*)d_in[14];
    const float* bn_v   = (const float*)d_in[15];
    float* out = (float*)d_out;

    float* ws   = (float*)d_ws;
    float* qv   = ws;                     // B*DO         = 16384
    float* wqkc = qv   + B*DO;            // B*NH*DO      = 131072
    float* wqkd = wqkc + B*NH*DO;         // 131072
    float* qbc  = wqkd + B*NH*DO;         // 512
    float* qbd  = qbc  + B*NH;            // 512
    float* gate = qbd  + B*NH;            // B*NH*HW      = 524288
    float* mz   = gate + B*NH*HW;         // B*NCH*NH*2   = 8192
    float* pvp  = mz   + B*NCH*NH*2;      // B*NCH*NH*DO  = 1048576
    float* attn = pvp  + B*NCH*NH*DO;     // B*DO         = 16384

    k1_qv <<<dim3(16, B),    256, 0, stream>>>(q, w_q, b_q, qv);
    k2_wqk<<<B*NH,           256, 0, stream>>>(qv, w_kc, b_kc, w_kd, b_kd, temp_c, temp_d,
                                               wqkc, wqkd, qbc, qbd);
    k3m   <<<dim3(NCH, B),   512, 0, stream>>>(v, wqkc, wqkd, qbc, qbd, gate, pvp, mz);
    k4c   <<<B,              256, 0, stream>>>(pvp, mz, w_v, b_v, attn);
    k5_out<<<dim3(DO, B),    256, 0, stream>>>(v, gate, attn, bn_g, bn_b, bn_m, bn_v, out);
}